// Round 16
// baseline (241.057 us; speedup 1.0000x reference)
//
#include <hip/hip_runtime.h>
#include <hip/hip_bf16.h>

// Model: one_hot -> 3x Conv2D(5,(4,4),(1,2),SAME) -> [B,S=1024,D=20]
//        -> 3x causal self-attention -> flatten -> 3x Dense(10)
// B=64, L=8192, S=1024, D=20.
// Attention uses bf16 MFMA (16x16x32, D padded to K=32). Scores |s|<<1 ->
// streaming softmax needs no max-subtraction (exact fp32 C-frag accumulation).
// R12: conv1 fused into conv2 — bit-identical, -14 us.
// R13: conv3 fused into proj layer-1 — bit-identical, -6 us.
// R14: proj 2/3 fused into attn 1/2 epilogues — neutral (work relocated).
// R15: K-frag preload + full chunk unroll (mask-only causality) — -6.5 us.
// R16: P scratch double-buffered by chunk parity (WAR hazard between chunk
// cc+1's P-writes and cc's P-reads removed) and the per-chunk
// `s_waitcnt lgkmcnt(0)` asm scheduling barrier deleted — ds ops to prow
// may-alias so the compiler preserves order and emits the minimal lgkmcnt(N)
// before pfrag use instead of a 32x-per-block full drain.

#define B_ 64
#define L_ 8192
#define S_ 1024
#define D_ 20

typedef unsigned short ushort_t;
typedef __attribute__((ext_vector_type(8))) short short8_t;  // 8 bf16 (4 VGPRs)
typedef __attribute__((ext_vector_type(4))) float f32x4_t;   // MFMA C/D

__device__ __forceinline__ ushort_t f2bf(float f) {          // RNE fp32->bf16
  unsigned u = __float_as_uint(f);
  return (ushort_t)((u + 0x7fffu + ((u >> 16) & 1u)) >> 16);
}
__device__ __forceinline__ float bf2f(ushort_t h) {
  return __uint_as_float(((unsigned)h) << 16);
}

// ---------------- fused conv1+conv2 ----------------
__global__ __launch_bounds__(256) void conv12_kernel(
    const int* __restrict__ inp,
    const float* __restrict__ W1c, const float* __restrict__ B1c,
    const float* __restrict__ W2c, const float* __restrict__ B2c,
    float* __restrict__ out) {    // c2 [B,4,2048,5]
  __shared__ float w1s[80], b1s[5], w2s[400], b2s[5];
  for (int j = threadIdx.x; j < 400; j += 256) w2s[j] = W2c[j];
  if (threadIdx.x < 80)      w1s[threadIdx.x]      = W1c[threadIdx.x];
  else if (threadIdx.x < 85) b1s[threadIdx.x - 80] = B1c[threadIdx.x - 80];
  else if (threadIdx.x < 90) b2s[threadIdx.x - 85] = B2c[threadIdx.x - 85];
  __syncthreads();
  const int idx = blockIdx.x * 256 + threadIdx.x;  // 131072 total
  const int b  = idx >> 11;
  const int wo = idx & 2047;
  const int* ib = inp + (size_t)b * L_;
  int iv[10];
#pragma unroll
  for (int t = 0; t < 10; ++t) {
    int g = 4 * wo - 3 + t;
    iv[t] = (g >= 0 && g < L_) ? ib[g] : -100;   // sentinel: no kh matches
  }
  float val[4][4][5];                            // [hi][pos][ci]
#pragma unroll
  for (int pos = 0; pos < 4; ++pos) {
    const int w1 = 2 * wo - 1 + pos;
    const bool okp = (w1 >= 0 && w1 < 4096);     // conv2 SAME padding -> 0
#pragma unroll
    for (int hi = 0; hi < 4; ++hi)
#pragma unroll
      for (int ci = 0; ci < 5; ++ci) val[hi][pos][ci] = okp ? b1s[ci] : 0.f;
    if (okp) {
#pragma unroll
      for (int kw = 0; kw < 4; ++kw) {
        const int gw = 2 * w1 - 1 + kw;
        if (gw >= 0 && gw < L_) {
          const int v = iv[2 * pos + kw];
#pragma unroll
          for (int hi = 0; hi < 4; ++hi) {
            const int kh = v - hi + 1;
            if (kh >= 0 && kh < 4) {
#pragma unroll
              for (int ci = 0; ci < 5; ++ci)
                val[hi][pos][ci] += w1s[(kh * 4 + kw) * 5 + ci];
            }
          }
        }
      }
    }
  }
  float acc[4][5];
#pragma unroll
  for (int h = 0; h < 4; ++h)
#pragma unroll
    for (int c = 0; c < 5; ++c) acc[h][c] = b2s[c];
#pragma unroll
  for (int kh = 0; kh < 4; ++kh)
#pragma unroll
    for (int kw = 0; kw < 4; ++kw)
#pragma unroll
      for (int ci = 0; ci < 5; ++ci) {
        const float* wp = w2s + ((kh * 4 + kw) * 5 + ci) * 5;
        float w0 = wp[0], w1v = wp[1], w2v = wp[2], w3 = wp[3], w4 = wp[4];
#pragma unroll
        for (int h = 0; h < 4; ++h) {
          int hi = h - 1 + kh;
          if (hi >= 0 && hi < 4) {
            float x = val[hi][kw][ci];
            acc[h][0] += w0 * x;  acc[h][1] += w1v * x; acc[h][2] += w2v * x;
            acc[h][3] += w3 * x;  acc[h][4] += w4 * x;
          }
        }
      }
  float* ob = out + (size_t)b * 4 * 2048 * 5;
#pragma unroll
  for (int h = 0; h < 4; ++h)
#pragma unroll
    for (int c = 0; c < 5; ++c) ob[(h * 2048 + wo) * 5 + c] = acc[h][c];
}

// ---------------- fused conv3 + proj (layer 1) ----------------
__global__ __launch_bounds__(256) void conv3_proj_kernel(
    const float* __restrict__ in,                 // c2 [B,4,2048,5]
    const float* __restrict__ W,  const float* __restrict__ Bi,
    const float* __restrict__ Kw, const float* __restrict__ Qw,
    const float* __restrict__ Vw,
    ushort_t* __restrict__ Qb, ushort_t* __restrict__ Kb,
    ushort_t* __restrict__ Vt) {
  constexpr int WIN = 2048;
  __shared__ float ws[400], bs[5];
  __shared__ float kw[400], qw[400], vw[400];
  for (int j = threadIdx.x; j < 400; j += 256) {
    ws[j] = W[j]; kw[j] = Kw[j]; qw[j] = Qw[j]; vw[j] = Vw[j];
  }
  if (threadIdx.x < 5) bs[threadIdx.x] = Bi[threadIdx.x];
  __syncthreads();
  const int r  = blockIdx.x * 256 + threadIdx.x;  // row in [0, 65536)
  const int b  = r >> 10;
  const int wo = r & 1023;
  float val[4][4][5];
#pragma unroll
  for (int hi = 0; hi < 4; ++hi) {
    const float* ir = in + ((size_t)b * 4 + hi) * WIN * 5;
#pragma unroll
    for (int kwp = 0; kwp < 4; ++kwp) {
      int wi = 2 * wo - 1 + kwp;
      bool ok = (wi >= 0 && wi < WIN);
#pragma unroll
      for (int ci = 0; ci < 5; ++ci) val[hi][kwp][ci] = ok ? ir[wi * 5 + ci] : 0.f;
    }
  }
  float acc[4][5];
#pragma unroll
  for (int h = 0; h < 4; ++h)
#pragma unroll
    for (int c = 0; c < 5; ++c) acc[h][c] = bs[c];
#pragma unroll
  for (int kh = 0; kh < 4; ++kh)
#pragma unroll
    for (int kwp = 0; kwp < 4; ++kwp)
#pragma unroll
      for (int ci = 0; ci < 5; ++ci) {
        const float* wp = ws + ((kh * 4 + kwp) * 5 + ci) * 5;
        float w0 = wp[0], w1 = wp[1], w2 = wp[2], w3 = wp[3], w4 = wp[4];
#pragma unroll
        for (int h = 0; h < 4; ++h) {
          int hi = h - 1 + kh;
          if (hi >= 0 && hi < 4) {
            float x = val[hi][kwp][ci];
            acc[h][0] += w0 * x; acc[h][1] += w1 * x; acc[h][2] += w2 * x;
            acc[h][3] += w3 * x; acc[h][4] += w4 * x;
          }
        }
      }
  float x[D_];
#pragma unroll
  for (int h = 0; h < 4; ++h)
#pragma unroll
    for (int c = 0; c < 5; ++c) x[h * 5 + c] = acc[h][c];
  float q[D_], k[D_], v[D_];
#pragma unroll
  for (int j = 0; j < D_; ++j) { q[j] = 0.f; k[j] = 0.f; v[j] = 0.f; }
#pragma unroll
  for (int i = 0; i < D_; ++i) {
#pragma unroll
    for (int j = 0; j < D_; ++j) {
      q[j] += x[i] * qw[i * D_ + j];
      k[j] += x[i] * kw[i * D_ + j];
      v[j] += x[i] * vw[i * D_ + j];
    }
  }
  const float sc = 0.22360679774997896f;  // 1/sqrt(20)
  ushort_t qt[32], kt[32];
#pragma unroll
  for (int j = 0; j < D_; ++j) { qt[j] = f2bf(q[j] * sc); kt[j] = f2bf(k[j]); }
#pragma unroll
  for (int j = D_; j < 32; ++j) { qt[j] = 0; kt[j] = 0; }
  int4* qd = (int4*)(Qb + (size_t)r * 32);
  int4* kd = (int4*)(Kb + (size_t)r * 32);
#pragma unroll
  for (int j = 0; j < 4; ++j) {
    qd[j] = *(const int4*)(qt + 8 * j);
    kd[j] = *(const int4*)(kt + 8 * j);
  }
  ushort_t* vbase = Vt + ((size_t)b * 32) * 1024 + wo;
#pragma unroll
  for (int d = 0; d < D_; ++d) vbase[d * 1024] = f2bf(v[d]);
}

// ---------------- causal attention via bf16 MFMA (+ optional fused proj) ----
// R16: P scratch double-buffered by chunk parity; no asm barrier in the hot
// loop (compiler-ordered may-alias LDS ops -> minimal lgkmcnt). Otherwise
// R15 core (K-frag preload, full unroll, mask-only causality).
#define TT_ 128
template <bool FUSE>
__global__ __launch_bounds__(256) void attn_kernel(
    const ushort_t* __restrict__ Qb, const ushort_t* __restrict__ Kb,
    const ushort_t* __restrict__ Vt, float* __restrict__ out,
    const float* __restrict__ Kw2, const float* __restrict__ Qw2,
    const float* __restrict__ Vw2,
    ushort_t* __restrict__ Qb2, ushort_t* __restrict__ Kb2,
    ushort_t* __restrict__ Vt2) {
  const int b     = blockIdx.y;
  const int strip = (blockIdx.x + 4 * (blockIdx.y >> 4)) & 15;
  const int q0    = strip * 64;
  const int tid   = threadIdx.x;
  const int w     = tid >> 6;             // wave 0..3
  const int lane  = tid & 63;
  const int n     = lane & 15;
  const int quad  = lane >> 4;
  const int qbase = q0 + 16 * w;
  __shared__ ushort_t kts[128 * 40];      // K tile, row stride 40 us (80 B)
  __shared__ ushort_t vts[32 * 136];      // V^T tile, row stride 136 us (272 B)
  __shared__ ushort_t pts[4][2][16 * 40]; // per-wave P scratch, x2 (chunk parity)
  __shared__ float    pw[1200];           // fused-proj weights K|Q|V (FUSE)
  __shared__ float    ox[4][320];         // per-wave normalized O rows (FUSE)
  if (FUSE) {
    float tmp[5];
#pragma unroll
    for (int u = 0; u < 5; ++u) {
      int j = tid + u * 256;
      if (j < 1200) {
        int m = j / 400, oo = j - m * 400;
        tmp[u] = (m == 0) ? Kw2[oo] : (m == 1) ? Qw2[oo] : Vw2[oo];
      }
    }
#pragma unroll
    for (int u = 0; u < 5; ++u) {
      int j = tid + u * 256;
      if (j < 1200) pw[j] = tmp[u];
    }
  }
  const ushort_t* KbB = Kb + (size_t)b * 1024 * 32;
  const ushort_t* VtB = Vt + (size_t)b * 32 * 1024;
  short8_t qfrag = *(const short8_t*)(Qb + ((size_t)(b * 1024 + qbase + n)) * 32 + quad * 8);
  f32x4_t oA = {0.f, 0.f, 0.f, 0.f};
  f32x4_t oB = {0.f, 0.f, 0.f, 0.f};
  f32x4_t lac = {0.f, 0.f, 0.f, 0.f};
  const f32x4_t zero = {0.f, 0.f, 0.f, 0.f};
  const int nt = q0 + 64;                 // block-uniform staging bound
  for (int t0 = 0; t0 < nt; t0 += TT_) {
    __syncthreads();
    for (int i = tid; i < 512; i += 256) {
      int row = i >> 2, qc = i & 3;
      *(int4*)(kts + row * 40 + qc * 8) =
          *(const int4*)(KbB + (size_t)(t0 + row) * 32 + qc * 8);
    }
    for (int i = tid; i < 320; i += 256) {
      int row = i >> 4, cc = i & 15;
      *(int4*)(vts + row * 136 + cc * 8) =
          *(const int4*)(VtB + (size_t)row * 1024 + t0 + cc * 8);
    }
    __syncthreads();
    // preload K fragments for all 4 chunks -> QK MFMAs have no LDS dependency
    short8_t kf[4][2];
#pragma unroll
    for (int cc = 0; cc < 4; ++cc) {
      kf[cc][0] = *(const short8_t*)(kts + (cc * 32 + n) * 40 + quad * 8);
      kf[cc][1] = *(const short8_t*)(kts + (cc * 32 + 16 + n) * 40 + quad * 8);
    }
#pragma unroll
    for (int cc = 0; cc < 4; ++cc) {
      const int tc = t0 + cc * 32;
      ushort_t* prow = pts[w][cc & 1];    // parity buffer: no WAR across chunks
      f32x4_t sA = __builtin_amdgcn_mfma_f32_16x16x32_bf16(qfrag, kf[cc][0], zero, 0, 0, 0);
      f32x4_t sB = __builtin_amdgcn_mfma_f32_16x16x32_bf16(qfrag, kf[cc][1], zero, 0, 0, 0);
#pragma unroll
      for (int r = 0; r < 4; ++r) {
        const int qg = qbase + quad * 4 + r;
        float pA = (tc + n      <= qg) ? __expf(sA[r]) : 0.f;
        float pB = (tc + 16 + n <= qg) ? __expf(sB[r]) : 0.f;
        ushort_t hA = f2bf(pA), hB = f2bf(pB);
        lac[r] += bf2f(hA) + bf2f(hB);    // consistent with bf16 P used in PV
        prow[(quad * 4 + r) * 40 + n]      = hA;
        prow[(quad * 4 + r) * 40 + 16 + n] = hB;
      }
      // same-wave LDS RAW: ds ops to prow may-alias -> compiler preserves
      // order and inserts the minimal lgkmcnt before pfrag use (no full drain)
      short8_t pfrag = *(const short8_t*)(prow + n * 40 + quad * 8);
      const short8_t vfA = *(const short8_t*)(vts + n * 136 + cc * 32 + quad * 8);
      const short8_t vfB = *(const short8_t*)(vts + (16 + n) * 136 + cc * 32 + quad * 8);
      oA = __builtin_amdgcn_mfma_f32_16x16x32_bf16(pfrag, vfA, oA, 0, 0, 0);
      oB = __builtin_amdgcn_mfma_f32_16x16x32_bf16(pfrag, vfB, oB, 0, 0, 0);
    }
  }
#pragma unroll
  for (int m = 1; m <= 8; m <<= 1) {
#pragma unroll
    for (int r = 0; r < 4; ++r) lac[r] += __shfl_xor(lac[r], m, 64);
  }
  if (!FUSE) {
    float* ob = out + ((size_t)(b * 1024 + qbase)) * 20;
#pragma unroll
    for (int r = 0; r < 4; ++r) {
      const float inv = 1.f / lac[r];
      const int qq = quad * 4 + r;
      ob[qq * 20 + n] = oA[r] * inv;                    // d = 0..15
      if (n < 4) ob[qq * 20 + 16 + n] = oB[r] * inv;    // d = 16..19
    }
  } else {
    float* oxw = ox[w];
#pragma unroll
    for (int r = 0; r < 4; ++r) {
      const float inv = 1.f / lac[r];
      const int qq = quad * 4 + r;
      oxw[qq * 20 + n] = oA[r] * inv;
      if (n < 4) oxw[qq * 20 + 16 + n] = oB[r] * inv;
    }
    __asm__ volatile("s_waitcnt lgkmcnt(0)" ::: "memory");  // wave-sync LDS RAW
    const int row  = lane >> 2;     // 0..15
    const int part = lane & 3;      // cols 5*part .. 5*part+4
    float x[D_];
#pragma unroll
    for (int i = 0; i < D_; ++i) x[i] = oxw[row * 20 + i];
    float qv[5], kv[5], vv[5];
#pragma unroll
    for (int jj = 0; jj < 5; ++jj) { qv[jj] = 0.f; kv[jj] = 0.f; vv[jj] = 0.f; }
#pragma unroll
    for (int i = 0; i < D_; ++i) {
      const float xi = x[i];
#pragma unroll
      for (int jj = 0; jj < 5; ++jj) {
        const int j = 5 * part + jj;
        kv[jj] += xi * pw[i * 20 + j];          // K block
        qv[jj] += xi * pw[400 + i * 20 + j];    // Q block
        vv[jj] += xi * pw[800 + i * 20 + j];    // V block
      }
    }
    const float sc = 0.22360679774997896f;
    const int rg = b * 1024 + qbase + row;
    const int s  = rg & 1023;
#pragma unroll
    for (int jj = 0; jj < 5; ++jj) {
      const int j = 5 * part + jj;
      Kb2[(size_t)rg * 32 + j] = f2bf(kv[jj]);
      Qb2[(size_t)rg * 32 + j] = f2bf(qv[jj] * sc);
      Vt2[(size_t)b * 32768 + (size_t)j * 1024 + s] = f2bf(vv[jj]);
    }
    if (part == 0) {
#pragma unroll
      for (int u = 0; u < 6; ++u)
        *(unsigned*)(Kb2 + (size_t)rg * 32 + 20 + 2 * u) = 0u;
    } else if (part == 1) {
#pragma unroll
      for (int u = 0; u < 6; ++u)
        *(unsigned*)(Qb2 + (size_t)rg * 32 + 20 + 2 * u) = 0u;
    }
  }
}

// ---------------- W1 transpose (once per call) ----------------
__global__ __launch_bounds__(256) void transpose_w1(
    const float* __restrict__ W1,   // [20480, 10]
    float* __restrict__ W1T) {      // [10, 20480]
  int idx = blockIdx.x * 256 + threadIdx.x;        // 204800 total
  int j = idx / 20480;
  int i = idx % 20480;
  W1T[idx] = W1[i * 10 + j];
}

// ---------------- dense head: stage 1 (partials, vectorized) ----------------
__global__ __launch_bounds__(256) void dense1_partial(
    const float* __restrict__ X,    // [64, 20480]
    const float* __restrict__ W1T,  // [10, 20480]
    float* __restrict__ part) {     // [64, 4, 10]
  const int b = blockIdx.x;
  const int s = blockIdx.y;
  const float4* xb = (const float4*)(X + (size_t)b * 20480 + s * 5120);
  float acc[10];
#pragma unroll
  for (int j = 0; j < 10; ++j) acc[j] = 0.f;
  for (int i = threadIdx.x; i < 1280; i += 256) {
    float4 xv = xb[i];
#pragma unroll
    for (int j = 0; j < 10; ++j) {
      float4 wv = ((const float4*)(W1T + (size_t)j * 20480 + s * 5120))[i];
      acc[j] += xv.x * wv.x + xv.y * wv.y + xv.z * wv.z + xv.w * wv.w;
    }
  }
  __shared__ float red[256][10];
#pragma unroll
  for (int j = 0; j < 10; ++j) red[threadIdx.x][j] = acc[j];
  __syncthreads();
  for (int off = 128; off > 0; off >>= 1) {
    if (threadIdx.x < (unsigned)off) {
#pragma unroll
      for (int j = 0; j < 10; ++j) red[threadIdx.x][j] += red[threadIdx.x + off][j];
    }
    __syncthreads();
  }
  if (threadIdx.x < 10) part[(b * 4 + s) * 10 + threadIdx.x] = red[0][threadIdx.x];
}

// ---------------- dense head: stage 2 (combine + dense2/3) ----------------
__global__ __launch_bounds__(64) void dense_final(
    const float* __restrict__ part,
    const float* __restrict__ B1,
    const float* __restrict__ W2, const float* __restrict__ B2,
    const float* __restrict__ W3, const float* __restrict__ B3,
    float* __restrict__ out) {
  const int b = blockIdx.x;
  __shared__ float y1[10], y2[10];
  if (threadIdx.x < 10) {
    int j = threadIdx.x;
    y1[j] = part[(b*4+0)*10 + j] + part[(b*4+1)*10 + j] +
            part[(b*4+2)*10 + j] + part[(b*4+3)*10 + j] + B1[j];
  }
  __syncthreads();
  if (threadIdx.x < 10) {
    int j = threadIdx.x;
    float s = B2[j];
#pragma unroll
    for (int i = 0; i < 10; ++i) s += y1[i] * W2[i * 10 + j];
    y2[j] = s;
  }
  __syncthreads();
  if (threadIdx.x < 10) {
    int j = threadIdx.x;
    float s = B3[j];
#pragma unroll
    for (int i = 0; i < 10; ++i) s += y2[i] * W3[i * 10 + j];
    out[b * 10 + j] = s;
  }
}

extern "C" void kernel_launch(void* const* d_in, const int* in_sizes, int n_in,
                              void* d_out, int out_size, void* d_ws, size_t ws_size,
                              hipStream_t stream) {
  const int*   inp = (const int*)d_in[0];
  const float* cw1 = (const float*)d_in[1];
  const float* cb1 = (const float*)d_in[2];
  const float* cw2 = (const float*)d_in[3];
  const float* cb2 = (const float*)d_in[4];
  const float* cw3 = (const float*)d_in[5];
  const float* cb3 = (const float*)d_in[6];
  const float* a1K = (const float*)d_in[7];
  const float* a1Q = (const float*)d_in[8];
  const float* a1V = (const float*)d_in[9];
  const float* a2K = (const float*)d_in[10];
  const float* a2Q = (const float*)d_in[11];
  const float* a2V = (const float*)d_in[12];
  const float* a3K = (const float*)d_in[13];
  const float* a3Q = (const float*)d_in[14];
  const float* a3V = (const float*)d_in[15];
  const float* dw1 = (const float*)d_in[16];
  const float* db1 = (const float*)d_in[17];
  const float* dw2 = (const float*)d_in[18];
  const float* db2 = (const float*)d_in[19];
  const float* dw3 = (const float*)d_in[20];
  const float* db3 = (const float*)d_in[21];
  float* outp = (float*)d_out;

  // workspace layout (float units)
  float* wsf = (float*)d_ws;
  ushort_t* qbA  = (ushort_t*)(wsf);            // [65536][32] bf16  [0 .. 1,048,576)
  ushort_t* kbA  = (ushort_t*)(wsf + 1048576);  //                   [1,048,576 .. 2,097,152)
  ushort_t* vtA  = (ushort_t*)(wsf + 2097152);  // [B,32,S]          [2,097,152 .. 3,145,728)
  float*    o    = wsf + 3145728;               // [B,S,20]          [3,145,728 .. 4,456,448)
  float*    part = wsf + 4456448;               // [64,4,10]
  float*    w1t  = wsf + 4459008;               // [10,20480]        ends 4,663,808
  ushort_t* qbB  = (ushort_t*)(wsf + 4663808);  // B-buffers overlap dead c2 region
  ushort_t* kbB  = (ushort_t*)(wsf + 5712384);  //   (c2 consumed before attn1 writes B)
  ushort_t* vtB  = (ushort_t*)(wsf + 6760960);  // ends 7,809,536
  float*    c2   = wsf + 5242880;               // [B,4,2048,5]      [5,242,880 .. 7,864,320)

  conv12_kernel<<<512, 256, 0, stream>>>(inp, cw1, cb1, cw2, cb2, c2);
  transpose_w1<<<800, 256, 0, stream>>>(dw1, w1t);

  conv3_proj_kernel<<<256, 256, 0, stream>>>(c2, cw3, cb3, a1K, a1Q, a1V, qbA, kbA, vtA);
  // attn1: reads A, fused proj(layer2) -> B
  attn_kernel<true><<<dim3(16, 64), 256, 0, stream>>>(
      qbA, kbA, vtA, nullptr, a2K, a2Q, a2V, qbB, kbB, vtB);
  // attn2: reads B, fused proj(layer3) -> A
  attn_kernel<true><<<dim3(16, 64), 256, 0, stream>>>(
      qbB, kbB, vtB, nullptr, a3K, a3Q, a3V, qbA, kbA, vtA);
  // attn3: reads A, writes o
  attn_kernel<false><<<dim3(16, 64), 256, 0, stream>>>(
      qbA, kbA, vtA, o, nullptr, nullptr, nullptr, nullptr, nullptr, nullptr);

  dense1_partial<<<dim3(64, 4), 256, 0, stream>>>(o, w1t, part);
  dense_final<<<64, 64, 0, stream>>>(part, db1, dw2, db2, dw3, db3, outp);
}

// Round 17
// 238.661 us; speedup vs baseline: 1.0100x; 1.0100x over previous
//
#include <hip/hip_runtime.h>
#include <hip/hip_bf16.h>

// Model: one_hot -> 3x Conv2D(5,(4,4),(1,2),SAME) -> [B,S=1024,D=20]
//        -> 3x causal self-attention -> flatten -> 3x Dense(10)
// B=64, L=8192, S=1024, D=20.
// Attention uses bf16 MFMA (16x16x32, D padded to K=32). Scores |s|<<1 ->
// streaming softmax needs no max-subtraction (exact fp32 C-frag accumulation).
// R12: conv1 fused into conv2 — bit-identical, -14 us.
// R13: conv3 fused into proj layer-1 — bit-identical, -6 us.
// R15: K-frag preload + full chunk unroll — -6.5 us (kept; R16's P-parity
//      variant regressed and is reverted).
// R17: launch consolidation: transpose_w1 folded into conv12 tail; dense1
//      partials folded into attn3 epilogue (deterministic per-strip partials
//      part2[b][16][10], summed in fixed order by dense_final — no atomics,
//      replay-deterministic). 8 -> 6 launches; o round-trip eliminated.

#define B_ 64
#define L_ 8192
#define S_ 1024
#define D_ 20

typedef unsigned short ushort_t;
typedef __attribute__((ext_vector_type(8))) short short8_t;  // 8 bf16 (4 VGPRs)
typedef __attribute__((ext_vector_type(4))) float f32x4_t;   // MFMA C/D

__device__ __forceinline__ ushort_t f2bf(float f) {          // RNE fp32->bf16
  unsigned u = __float_as_uint(f);
  return (ushort_t)((u + 0x7fffu + ((u >> 16) & 1u)) >> 16);
}
__device__ __forceinline__ float bf2f(ushort_t h) {
  return __uint_as_float(((unsigned)h) << 16);
}

// ---------------- fused conv1+conv2 (+ W1 transpose tail) ----------------
__global__ __launch_bounds__(256) void conv12_kernel(
    const int* __restrict__ inp,
    const float* __restrict__ W1c, const float* __restrict__ B1c,
    const float* __restrict__ W2c, const float* __restrict__ B2c,
    float* __restrict__ out,                      // c2 [B,4,2048,5]
    const float* __restrict__ W1d,                // dense W1 [20480,10]
    float* __restrict__ W1T) {                    // [10,20480]
  __shared__ float w1s[80], b1s[5], w2s[400], b2s[5];
  for (int j = threadIdx.x; j < 400; j += 256) w2s[j] = W2c[j];
  if (threadIdx.x < 80)      w1s[threadIdx.x]      = W1c[threadIdx.x];
  else if (threadIdx.x < 85) b1s[threadIdx.x - 80] = B1c[threadIdx.x - 80];
  else if (threadIdx.x < 90) b2s[threadIdx.x - 85] = B2c[threadIdx.x - 85];
  __syncthreads();
  const int idx = blockIdx.x * 256 + threadIdx.x;  // 131072 total
  const int b  = idx >> 11;
  const int wo = idx & 2047;
  const int* ib = inp + (size_t)b * L_;
  int iv[10];
#pragma unroll
  for (int t = 0; t < 10; ++t) {
    int g = 4 * wo - 3 + t;
    iv[t] = (g >= 0 && g < L_) ? ib[g] : -100;   // sentinel: no kh matches
  }
  float val[4][4][5];                            // [hi][pos][ci]
#pragma unroll
  for (int pos = 0; pos < 4; ++pos) {
    const int w1 = 2 * wo - 1 + pos;
    const bool okp = (w1 >= 0 && w1 < 4096);     // conv2 SAME padding -> 0
#pragma unroll
    for (int hi = 0; hi < 4; ++hi)
#pragma unroll
      for (int ci = 0; ci < 5; ++ci) val[hi][pos][ci] = okp ? b1s[ci] : 0.f;
    if (okp) {
#pragma unroll
      for (int kw = 0; kw < 4; ++kw) {
        const int gw = 2 * w1 - 1 + kw;
        if (gw >= 0 && gw < L_) {
          const int v = iv[2 * pos + kw];
#pragma unroll
          for (int hi = 0; hi < 4; ++hi) {
            const int kh = v - hi + 1;
            if (kh >= 0 && kh < 4) {
#pragma unroll
              for (int ci = 0; ci < 5; ++ci)
                val[hi][pos][ci] += w1s[(kh * 4 + kw) * 5 + ci];
            }
          }
        }
      }
    }
  }
  float acc[4][5];
#pragma unroll
  for (int h = 0; h < 4; ++h)
#pragma unroll
    for (int c = 0; c < 5; ++c) acc[h][c] = b2s[c];
#pragma unroll
  for (int kh = 0; kh < 4; ++kh)
#pragma unroll
    for (int kw = 0; kw < 4; ++kw)
#pragma unroll
      for (int ci = 0; ci < 5; ++ci) {
        const float* wp = w2s + ((kh * 4 + kw) * 5 + ci) * 5;
        float w0 = wp[0], w1v = wp[1], w2v = wp[2], w3 = wp[3], w4 = wp[4];
#pragma unroll
        for (int h = 0; h < 4; ++h) {
          int hi = h - 1 + kh;
          if (hi >= 0 && hi < 4) {
            float x = val[hi][kw][ci];
            acc[h][0] += w0 * x;  acc[h][1] += w1v * x; acc[h][2] += w2v * x;
            acc[h][3] += w3 * x;  acc[h][4] += w4 * x;
          }
        }
      }
  float* ob = out + (size_t)b * 4 * 2048 * 5;
#pragma unroll
  for (int h = 0; h < 4; ++h)
#pragma unroll
    for (int c = 0; c < 5; ++c) ob[(h * 2048 + wo) * 5 + c] = acc[h][c];
  // ---- tail: W1 transpose (grid-stride over 204800 elements) ----
  for (int j = idx; j < 204800; j += 131072) {
    int col = j / 20480, i2 = j - col * 20480;
    W1T[j] = W1d[i2 * 10 + col];
  }
}

// ---------------- fused conv3 + proj (layer 1) ----------------
__global__ __launch_bounds__(256) void conv3_proj_kernel(
    const float* __restrict__ in,                 // c2 [B,4,2048,5]
    const float* __restrict__ W,  const float* __restrict__ Bi,
    const float* __restrict__ Kw, const float* __restrict__ Qw,
    const float* __restrict__ Vw,
    ushort_t* __restrict__ Qb, ushort_t* __restrict__ Kb,
    ushort_t* __restrict__ Vt) {
  constexpr int WIN = 2048;
  __shared__ float ws[400], bs[5];
  __shared__ float kw[400], qw[400], vw[400];
  for (int j = threadIdx.x; j < 400; j += 256) {
    ws[j] = W[j]; kw[j] = Kw[j]; qw[j] = Qw[j]; vw[j] = Vw[j];
  }
  if (threadIdx.x < 5) bs[threadIdx.x] = Bi[threadIdx.x];
  __syncthreads();
  const int r  = blockIdx.x * 256 + threadIdx.x;  // row in [0, 65536)
  const int b  = r >> 10;
  const int wo = r & 1023;
  float val[4][4][5];
#pragma unroll
  for (int hi = 0; hi < 4; ++hi) {
    const float* ir = in + ((size_t)b * 4 + hi) * WIN * 5;
#pragma unroll
    for (int kwp = 0; kwp < 4; ++kwp) {
      int wi = 2 * wo - 1 + kwp;
      bool ok = (wi >= 0 && wi < WIN);
#pragma unroll
      for (int ci = 0; ci < 5; ++ci) val[hi][kwp][ci] = ok ? ir[wi * 5 + ci] : 0.f;
    }
  }
  float acc[4][5];
#pragma unroll
  for (int h = 0; h < 4; ++h)
#pragma unroll
    for (int c = 0; c < 5; ++c) acc[h][c] = bs[c];
#pragma unroll
  for (int kh = 0; kh < 4; ++kh)
#pragma unroll
    for (int kwp = 0; kwp < 4; ++kwp)
#pragma unroll
      for (int ci = 0; ci < 5; ++ci) {
        const float* wp = ws + ((kh * 4 + kwp) * 5 + ci) * 5;
        float w0 = wp[0], w1 = wp[1], w2 = wp[2], w3 = wp[3], w4 = wp[4];
#pragma unroll
        for (int h = 0; h < 4; ++h) {
          int hi = h - 1 + kh;
          if (hi >= 0 && hi < 4) {
            float x = val[hi][kwp][ci];
            acc[h][0] += w0 * x; acc[h][1] += w1 * x; acc[h][2] += w2 * x;
            acc[h][3] += w3 * x; acc[h][4] += w4 * x;
          }
        }
      }
  float x[D_];
#pragma unroll
  for (int h = 0; h < 4; ++h)
#pragma unroll
    for (int c = 0; c < 5; ++c) x[h * 5 + c] = acc[h][c];
  float q[D_], k[D_], v[D_];
#pragma unroll
  for (int j = 0; j < D_; ++j) { q[j] = 0.f; k[j] = 0.f; v[j] = 0.f; }
#pragma unroll
  for (int i = 0; i < D_; ++i) {
#pragma unroll
    for (int j = 0; j < D_; ++j) {
      q[j] += x[i] * qw[i * D_ + j];
      k[j] += x[i] * kw[i * D_ + j];
      v[j] += x[i] * vw[i * D_ + j];
    }
  }
  const float sc = 0.22360679774997896f;  // 1/sqrt(20)
  ushort_t qt[32], kt[32];
#pragma unroll
  for (int j = 0; j < D_; ++j) { qt[j] = f2bf(q[j] * sc); kt[j] = f2bf(k[j]); }
#pragma unroll
  for (int j = D_; j < 32; ++j) { qt[j] = 0; kt[j] = 0; }
  int4* qd = (int4*)(Qb + (size_t)r * 32);
  int4* kd = (int4*)(Kb + (size_t)r * 32);
#pragma unroll
  for (int j = 0; j < 4; ++j) {
    qd[j] = *(const int4*)(qt + 8 * j);
    kd[j] = *(const int4*)(kt + 8 * j);
  }
  ushort_t* vbase = Vt + ((size_t)b * 32) * 1024 + wo;
#pragma unroll
  for (int d = 0; d < D_; ++d) vbase[d * 1024] = f2bf(v[d]);
}

// ---------------- causal attention via bf16 MFMA ----------------
// Core = R15 (proven best): K-frag preload, full chunk unroll with mask-only
// causality, single per-wave P scratch with wave-sync lgkmcnt barrier.
// FUSE=true : epilogue projects this block's O rows into next layer's
//             Qb2/Kb2/Vt2 (proj_kernel's exact i-ascending order).
// FUSE=false: epilogue computes this block's deterministic dense1 partial
//             (10 floats) into part2[b][strip][10]; o never materialized.
#define TT_ 128
template <bool FUSE>
__global__ __launch_bounds__(256) void attn_kernel(
    const ushort_t* __restrict__ Qb, const ushort_t* __restrict__ Kb,
    const ushort_t* __restrict__ Vt,
    const float* __restrict__ Kw2, const float* __restrict__ Qw2,
    const float* __restrict__ Vw2,
    ushort_t* __restrict__ Qb2, ushort_t* __restrict__ Kb2,
    ushort_t* __restrict__ Vt2,
    const float* __restrict__ W1T,   // !FUSE: [10,20480]
    float* __restrict__ part2) {     // !FUSE: [64,16,10]
  const int b     = blockIdx.y;
  const int strip = (blockIdx.x + 4 * (blockIdx.y >> 4)) & 15;
  const int q0    = strip * 64;
  const int tid   = threadIdx.x;
  const int w     = tid >> 6;             // wave 0..3
  const int lane  = tid & 63;
  const int n     = lane & 15;
  const int quad  = lane >> 4;
  const int qbase = q0 + 16 * w;
  __shared__ ushort_t kts[128 * 40];      // K tile, row stride 40 us (80 B)
  __shared__ ushort_t vts[32 * 136];      // V^T tile, row stride 136 us (272 B)
  __shared__ ushort_t pts[4][16 * 40];    // per-wave P scratch, stride 40 us
  // FUSE:  [0..1200) proj weights K|Q|V, [1200..2480) ox (4x320)
  // !FUSE: [0..1280) ox flat, [1280..3840) red (256x10)
  __shared__ float extraf[FUSE ? 2480 : 3840];
  if (FUSE) {
    float tmp[5];
#pragma unroll
    for (int u = 0; u < 5; ++u) {
      int j = tid + u * 256;
      if (j < 1200) {
        int m = j / 400, oo = j - m * 400;
        tmp[u] = (m == 0) ? Kw2[oo] : (m == 1) ? Qw2[oo] : Vw2[oo];
      }
    }
#pragma unroll
    for (int u = 0; u < 5; ++u) {
      int j = tid + u * 256;
      if (j < 1200) extraf[j] = tmp[u];
    }
  }
  const ushort_t* KbB = Kb + (size_t)b * 1024 * 32;
  const ushort_t* VtB = Vt + (size_t)b * 32 * 1024;
  short8_t qfrag = *(const short8_t*)(Qb + ((size_t)(b * 1024 + qbase + n)) * 32 + quad * 8);
  f32x4_t oA = {0.f, 0.f, 0.f, 0.f};
  f32x4_t oB = {0.f, 0.f, 0.f, 0.f};
  f32x4_t lac = {0.f, 0.f, 0.f, 0.f};
  const f32x4_t zero = {0.f, 0.f, 0.f, 0.f};
  const int nt = q0 + 64;                 // block-uniform staging bound
  ushort_t* prow = pts[w];
  for (int t0 = 0; t0 < nt; t0 += TT_) {
    __syncthreads();
    for (int i = tid; i < 512; i += 256) {
      int row = i >> 2, qc = i & 3;
      *(int4*)(kts + row * 40 + qc * 8) =
          *(const int4*)(KbB + (size_t)(t0 + row) * 32 + qc * 8);
    }
    for (int i = tid; i < 320; i += 256) {
      int row = i >> 4, cc = i & 15;
      *(int4*)(vts + row * 136 + cc * 8) =
          *(const int4*)(VtB + (size_t)row * 1024 + t0 + cc * 8);
    }
    __syncthreads();
    // preload K fragments for all 4 chunks -> QK MFMAs have no LDS dependency
    short8_t kf[4][2];
#pragma unroll
    for (int cc = 0; cc < 4; ++cc) {
      kf[cc][0] = *(const short8_t*)(kts + (cc * 32 + n) * 40 + quad * 8);
      kf[cc][1] = *(const short8_t*)(kts + (cc * 32 + 16 + n) * 40 + quad * 8);
    }
#pragma unroll
    for (int cc = 0; cc < 4; ++cc) {
      const int tc = t0 + cc * 32;
      f32x4_t sA = __builtin_amdgcn_mfma_f32_16x16x32_bf16(qfrag, kf[cc][0], zero, 0, 0, 0);
      f32x4_t sB = __builtin_amdgcn_mfma_f32_16x16x32_bf16(qfrag, kf[cc][1], zero, 0, 0, 0);
#pragma unroll
      for (int r = 0; r < 4; ++r) {
        const int qg = qbase + quad * 4 + r;
        float pA = (tc + n      <= qg) ? __expf(sA[r]) : 0.f;
        float pB = (tc + 16 + n <= qg) ? __expf(sB[r]) : 0.f;
        ushort_t hA = f2bf(pA), hB = f2bf(pB);
        lac[r] += bf2f(hA) + bf2f(hB);    // consistent with bf16 P used in PV
        prow[(quad * 4 + r) * 40 + n]      = hA;
        prow[(quad * 4 + r) * 40 + 16 + n] = hB;
      }
      __asm__ volatile("s_waitcnt lgkmcnt(0)" ::: "memory");  // wave-sync LDS RAW
      short8_t pfrag = *(const short8_t*)(prow + n * 40 + quad * 8);
      const short8_t vfA = *(const short8_t*)(vts + n * 136 + cc * 32 + quad * 8);
      const short8_t vfB = *(const short8_t*)(vts + (16 + n) * 136 + cc * 32 + quad * 8);
      oA = __builtin_amdgcn_mfma_f32_16x16x32_bf16(pfrag, vfA, oA, 0, 0, 0);
      oB = __builtin_amdgcn_mfma_f32_16x16x32_bf16(pfrag, vfB, oB, 0, 0, 0);
    }
  }
#pragma unroll
  for (int m = 1; m <= 8; m <<= 1) {
#pragma unroll
    for (int r = 0; r < 4; ++r) lac[r] += __shfl_xor(lac[r], m, 64);
  }
  if (FUSE) {
    float* pw  = extraf;
    float* oxw = extraf + 1200 + w * 320;
#pragma unroll
    for (int r = 0; r < 4; ++r) {
      const float inv = 1.f / lac[r];
      const int qq = quad * 4 + r;
      oxw[qq * 20 + n] = oA[r] * inv;
      if (n < 4) oxw[qq * 20 + 16 + n] = oB[r] * inv;
    }
    __asm__ volatile("s_waitcnt lgkmcnt(0)" ::: "memory");  // wave-sync LDS RAW
    const int row  = lane >> 2;     // 0..15
    const int part = lane & 3;      // cols 5*part .. 5*part+4
    float x[D_];
#pragma unroll
    for (int i = 0; i < D_; ++i) x[i] = oxw[row * 20 + i];
    float qv[5], kv[5], vv[5];
#pragma unroll
    for (int jj = 0; jj < 5; ++jj) { qv[jj] = 0.f; kv[jj] = 0.f; vv[jj] = 0.f; }
#pragma unroll
    for (int i = 0; i < D_; ++i) {
      const float xi = x[i];
#pragma unroll
      for (int jj = 0; jj < 5; ++jj) {
        const int j = 5 * part + jj;
        kv[jj] += xi * pw[i * 20 + j];          // K block
        qv[jj] += xi * pw[400 + i * 20 + j];    // Q block
        vv[jj] += xi * pw[800 + i * 20 + j];    // V block
      }
    }
    const float sc = 0.22360679774997896f;
    const int rg = b * 1024 + qbase + row;
    const int s  = rg & 1023;
#pragma unroll
    for (int jj = 0; jj < 5; ++jj) {
      const int j = 5 * part + jj;
      Kb2[(size_t)rg * 32 + j] = f2bf(kv[jj]);
      Qb2[(size_t)rg * 32 + j] = f2bf(qv[jj] * sc);
      Vt2[(size_t)b * 32768 + (size_t)j * 1024 + s] = f2bf(vv[jj]);
    }
    if (part == 0) {
#pragma unroll
      for (int u = 0; u < 6; ++u)
        *(unsigned*)(Kb2 + (size_t)rg * 32 + 20 + 2 * u) = 0u;
    } else if (part == 1) {
#pragma unroll
      for (int u = 0; u < 6; ++u)
        *(unsigned*)(Qb2 + (size_t)rg * 32 + 20 + 2 * u) = 0u;
    }
  } else {
    // ---- fused dense1 partial over this block's 64 rows ----
    float* oxflat = extraf;              // [1280] = X[b, q0*20 .. q0*20+1280)
    float* oxw    = oxflat + w * 320;    // this wave's 16 rows (contiguous)
    float* red    = extraf + 1280;       // [256][10]
#pragma unroll
    for (int r = 0; r < 4; ++r) {
      const float inv = 1.f / lac[r];
      const int qq = quad * 4 + r;
      oxw[qq * 20 + n] = oA[r] * inv;
      if (n < 4) oxw[qq * 20 + 16 + n] = oB[r] * inv;
    }
    __syncthreads();                     // all waves' ox visible
    float acc[10];
#pragma unroll
    for (int j = 0; j < 10; ++j) acc[j] = 0.f;
    const float* wb = W1T;               // [10][20480]
    const int base = q0 * 20;
#pragma unroll
    for (int k = 0; k < 5; ++k) {
      const int il = tid + 256 * k;
      const float xv = oxflat[il];
#pragma unroll
      for (int j = 0; j < 10; ++j)
        acc[j] += xv * wb[(size_t)j * 20480 + base + il];  // lane-coalesced
    }
#pragma unroll
    for (int j = 0; j < 10; ++j) red[tid * 10 + j] = acc[j];
    __syncthreads();
    for (int off = 128; off > 0; off >>= 1) {
      if (tid < off) {
#pragma unroll
        for (int j = 0; j < 10; ++j) red[tid * 10 + j] += red[(tid + off) * 10 + j];
      }
      __syncthreads();
    }
    if (tid < 10) part2[((b << 4) + strip) * 10 + tid] = red[tid];
  }
}

// ---------------- dense head: combine strips + dense2/3 ----------------
__global__ __launch_bounds__(64) void dense_final(
    const float* __restrict__ part2,   // [64,16,10], strip-ordered
    const float* __restrict__ B1,
    const float* __restrict__ W2, const float* __restrict__ B2,
    const float* __restrict__ W3, const float* __restrict__ B3,
    float* __restrict__ out) {
  const int b = blockIdx.x;
  __shared__ float y1[10], y2[10];
  if (threadIdx.x < 10) {
    int j = threadIdx.x;
    float s = 0.f;
#pragma unroll
    for (int st = 0; st < 16; ++st) s += part2[((b << 4) + st) * 10 + j];
    y1[j] = s + B1[j];
  }
  __syncthreads();
  if (threadIdx.x < 10) {
    int j = threadIdx.x;
    float s = B2[j];
#pragma unroll
    for (int i = 0; i < 10; ++i) s += y1[i] * W2[i * 10 + j];
    y2[j] = s;
  }
  __syncthreads();
  if (threadIdx.x < 10) {
    int j = threadIdx.x;
    float s = B3[j];
#pragma unroll
    for (int i = 0; i < 10; ++i) s += y2[i] * W3[i * 10 + j];
    out[b * 10 + j] = s;
  }
}

extern "C" void kernel_launch(void* const* d_in, const int* in_sizes, int n_in,
                              void* d_out, int out_size, void* d_ws, size_t ws_size,
                              hipStream_t stream) {
  const int*   inp = (const int*)d_in[0];
  const float* cw1 = (const float*)d_in[1];
  const float* cb1 = (const float*)d_in[2];
  const float* cw2 = (const float*)d_in[3];
  const float* cb2 = (const float*)d_in[4];
  const float* cw3 = (const float*)d_in[5];
  const float* cb3 = (const float*)d_in[6];
  const float* a1K = (const float*)d_in[7];
  const float* a1Q = (const float*)d_in[8];
  const float* a1V = (const float*)d_in[9];
  const float* a2K = (const float*)d_in[10];
  const float* a2Q = (const float*)d_in[11];
  const float* a2V = (const float*)d_in[12];
  const float* a3K = (const float*)d_in[13];
  const float* a3Q = (const float*)d_in[14];
  const float* a3V = (const float*)d_in[15];
  const float* dw1 = (const float*)d_in[16];
  const float* db1 = (const float*)d_in[17];
  const float* dw2 = (const float*)d_in[18];
  const float* db2 = (const float*)d_in[19];
  const float* dw3 = (const float*)d_in[20];
  const float* db3 = (const float*)d_in[21];
  float* outp = (float*)d_out;

  // workspace layout (float units)
  float* wsf = (float*)d_ws;
  ushort_t* qbA  = (ushort_t*)(wsf);            // [65536][32] bf16  [0 .. 1,048,576)
  ushort_t* kbA  = (ushort_t*)(wsf + 1048576);  //                   [1,048,576 .. 2,097,152)
  ushort_t* vtA  = (ushort_t*)(wsf + 2097152);  // [B,32,S]          [2,097,152 .. 3,145,728)
  float*    part2= wsf + 4456448;               // [64,16,10]        [4,456,448 .. 4,466,688)
  float*    w1t  = wsf + 4466688;               // [10,20480]        ends 4,671,488
  ushort_t* qbB  = (ushort_t*)(wsf + 4671488);  // ends 5,195,776
  ushort_t* kbB  = (ushort_t*)(wsf + 5712384);  // B-buffers overlap dead c2 region
  ushort_t* vtB  = (ushort_t*)(wsf + 6760960);  //   (c2 consumed before attn1 writes B)
  float*    c2   = wsf + 5242880;               // [B,4,2048,5]      [5,242,880 .. 7,864,320)

  conv12_kernel<<<512, 256, 0, stream>>>(inp, cw1, cb1, cw2, cb2, c2, dw1, w1t);

  conv3_proj_kernel<<<256, 256, 0, stream>>>(c2, cw3, cb3, a1K, a1Q, a1V, qbA, kbA, vtA);
  // attn1: reads A, fused proj(layer2) -> B
  attn_kernel<true><<<dim3(16, 64), 256, 0, stream>>>(
      qbA, kbA, vtA, a2K, a2Q, a2V, qbB, kbB, vtB, nullptr, nullptr);
  // attn2: reads B, fused proj(layer3) -> A
  attn_kernel<true><<<dim3(16, 64), 256, 0, stream>>>(
      qbB, kbB, vtB, a3K, a3Q, a3V, qbA, kbA, vtA, nullptr, nullptr);
  // attn3: reads A, fused dense1 partial -> part2
  attn_kernel<false><<<dim3(16, 64), 256, 0, stream>>>(
      qbA, kbA, vtA, nullptr, nullptr, nullptr, nullptr, nullptr, nullptr,
      w1t, part2);

  dense_final<<<64, 64, 0, stream>>>(part2, db1, dw2, db2, dw3, db3, outp);
}

// Round 18
// 217.718 us; speedup vs baseline: 1.1072x; 1.0962x over previous
//
#include <hip/hip_runtime.h>
#include <hip/hip_bf16.h>

// Model: one_hot -> 3x Conv2D(5,(4,4),(1,2),SAME) -> [B,S=1024,D=20]
//        -> 3x causal self-attention -> flatten -> 3x Dense(10)
// B=64, L=8192, S=1024, D=20.
// R12: conv1 fused into conv2. R13: conv3 fused into proj layer-1.
// R15: K-frag preload + full chunk unroll. R17: 6-launch consolidation
// (W1 transpose in conv12 tail; dense1 partial in attn3 epilogue).
// R18: P LDS round-trip eliminated. QK computed transposed
// (S^T = mfma(Kfrag, Qfrag) — same registers, operands swapped). The 16x16
// C/D layout (row=quad*4+r, col=n) IS the B-operand layout of
// mfma_f32_16x16x16_bf16 (k=quad*4+j, n=lane&15), so P^T feeds PV directly
// from registers: O^T = mfma_16x16x16(V^T-frag, P^T-frag, O^T). Removes
// 8 bank-conflicting ds_write_u16 + full lgkmcnt drain + b128 re-read per
// chunk (R17 counters: 1.77M conflict cycles, 50.8us/attn). l reduced
// per-column via shfl_xor(16,32).

#define B_ 64
#define L_ 8192
#define S_ 1024
#define D_ 20

typedef unsigned short ushort_t;
typedef __attribute__((ext_vector_type(8))) short short8_t;  // 8 bf16 (4 VGPRs)
typedef __attribute__((ext_vector_type(4))) short short4_t;  // 4 bf16 (2 VGPRs)
typedef __attribute__((ext_vector_type(4))) float f32x4_t;   // MFMA C/D

__device__ __forceinline__ ushort_t f2bf(float f) {          // RNE fp32->bf16
  unsigned u = __float_as_uint(f);
  return (ushort_t)((u + 0x7fffu + ((u >> 16) & 1u)) >> 16);
}
__device__ __forceinline__ float bf2f(ushort_t h) {
  return __uint_as_float(((unsigned)h) << 16);
}

// ---------------- fused conv1+conv2 (+ W1 transpose tail) ----------------
__global__ __launch_bounds__(256) void conv12_kernel(
    const int* __restrict__ inp,
    const float* __restrict__ W1c, const float* __restrict__ B1c,
    const float* __restrict__ W2c, const float* __restrict__ B2c,
    float* __restrict__ out,                      // c2 [B,4,2048,5]
    const float* __restrict__ W1d,                // dense W1 [20480,10]
    float* __restrict__ W1T) {                    // [10,20480]
  __shared__ float w1s[80], b1s[5], w2s[400], b2s[5];
  for (int j = threadIdx.x; j < 400; j += 256) w2s[j] = W2c[j];
  if (threadIdx.x < 80)      w1s[threadIdx.x]      = W1c[threadIdx.x];
  else if (threadIdx.x < 85) b1s[threadIdx.x - 80] = B1c[threadIdx.x - 80];
  else if (threadIdx.x < 90) b2s[threadIdx.x - 85] = B2c[threadIdx.x - 85];
  __syncthreads();
  const int idx = blockIdx.x * 256 + threadIdx.x;  // 131072 total
  const int b  = idx >> 11;
  const int wo = idx & 2047;
  const int* ib = inp + (size_t)b * L_;
  int iv[10];
#pragma unroll
  for (int t = 0; t < 10; ++t) {
    int g = 4 * wo - 3 + t;
    iv[t] = (g >= 0 && g < L_) ? ib[g] : -100;   // sentinel: no kh matches
  }
  float val[4][4][5];                            // [hi][pos][ci]
#pragma unroll
  for (int pos = 0; pos < 4; ++pos) {
    const int w1 = 2 * wo - 1 + pos;
    const bool okp = (w1 >= 0 && w1 < 4096);     // conv2 SAME padding -> 0
#pragma unroll
    for (int hi = 0; hi < 4; ++hi)
#pragma unroll
      for (int ci = 0; ci < 5; ++ci) val[hi][pos][ci] = okp ? b1s[ci] : 0.f;
    if (okp) {
#pragma unroll
      for (int kw = 0; kw < 4; ++kw) {
        const int gw = 2 * w1 - 1 + kw;
        if (gw >= 0 && gw < L_) {
          const int v = iv[2 * pos + kw];
#pragma unroll
          for (int hi = 0; hi < 4; ++hi) {
            const int kh = v - hi + 1;
            if (kh >= 0 && kh < 4) {
#pragma unroll
              for (int ci = 0; ci < 5; ++ci)
                val[hi][pos][ci] += w1s[(kh * 4 + kw) * 5 + ci];
            }
          }
        }
      }
    }
  }
  float acc[4][5];
#pragma unroll
  for (int h = 0; h < 4; ++h)
#pragma unroll
    for (int c = 0; c < 5; ++c) acc[h][c] = b2s[c];
#pragma unroll
  for (int kh = 0; kh < 4; ++kh)
#pragma unroll
    for (int kw = 0; kw < 4; ++kw)
#pragma unroll
      for (int ci = 0; ci < 5; ++ci) {
        const float* wp = w2s + ((kh * 4 + kw) * 5 + ci) * 5;
        float w0 = wp[0], w1v = wp[1], w2v = wp[2], w3 = wp[3], w4 = wp[4];
#pragma unroll
        for (int h = 0; h < 4; ++h) {
          int hi = h - 1 + kh;
          if (hi >= 0 && hi < 4) {
            float x = val[hi][kw][ci];
            acc[h][0] += w0 * x;  acc[h][1] += w1v * x; acc[h][2] += w2v * x;
            acc[h][3] += w3 * x;  acc[h][4] += w4 * x;
          }
        }
      }
  float* ob = out + (size_t)b * 4 * 2048 * 5;
#pragma unroll
  for (int h = 0; h < 4; ++h)
#pragma unroll
    for (int c = 0; c < 5; ++c) ob[(h * 2048 + wo) * 5 + c] = acc[h][c];
  // ---- tail: W1 transpose (grid-stride over 204800 elements) ----
  for (int j = idx; j < 204800; j += 131072) {
    int col = j / 20480, i2 = j - col * 20480;
    W1T[j] = W1d[i2 * 10 + col];
  }
}

// ---------------- fused conv3 + proj (layer 1) ----------------
__global__ __launch_bounds__(256) void conv3_proj_kernel(
    const float* __restrict__ in,                 // c2 [B,4,2048,5]
    const float* __restrict__ W,  const float* __restrict__ Bi,
    const float* __restrict__ Kw, const float* __restrict__ Qw,
    const float* __restrict__ Vw,
    ushort_t* __restrict__ Qb, ushort_t* __restrict__ Kb,
    ushort_t* __restrict__ Vt) {
  constexpr int WIN = 2048;
  __shared__ float ws[400], bs[5];
  __shared__ float kw[400], qw[400], vw[400];
  for (int j = threadIdx.x; j < 400; j += 256) {
    ws[j] = W[j]; kw[j] = Kw[j]; qw[j] = Qw[j]; vw[j] = Vw[j];
  }
  if (threadIdx.x < 5) bs[threadIdx.x] = Bi[threadIdx.x];
  __syncthreads();
  const int r  = blockIdx.x * 256 + threadIdx.x;  // row in [0, 65536)
  const int b  = r >> 10;
  const int wo = r & 1023;
  float val[4][4][5];
#pragma unroll
  for (int hi = 0; hi < 4; ++hi) {
    const float* ir = in + ((size_t)b * 4 + hi) * WIN * 5;
#pragma unroll
    for (int kwp = 0; kwp < 4; ++kwp) {
      int wi = 2 * wo - 1 + kwp;
      bool ok = (wi >= 0 && wi < WIN);
#pragma unroll
      for (int ci = 0; ci < 5; ++ci) val[hi][kwp][ci] = ok ? ir[wi * 5 + ci] : 0.f;
    }
  }
  float acc[4][5];
#pragma unroll
  for (int h = 0; h < 4; ++h)
#pragma unroll
    for (int c = 0; c < 5; ++c) acc[h][c] = bs[c];
#pragma unroll
  for (int kh = 0; kh < 4; ++kh)
#pragma unroll
    for (int kwp = 0; kwp < 4; ++kwp)
#pragma unroll
      for (int ci = 0; ci < 5; ++ci) {
        const float* wp = ws + ((kh * 4 + kwp) * 5 + ci) * 5;
        float w0 = wp[0], w1 = wp[1], w2 = wp[2], w3 = wp[3], w4 = wp[4];
#pragma unroll
        for (int h = 0; h < 4; ++h) {
          int hi = h - 1 + kh;
          if (hi >= 0 && hi < 4) {
            float x = val[hi][kwp][ci];
            acc[h][0] += w0 * x; acc[h][1] += w1 * x; acc[h][2] += w2 * x;
            acc[h][3] += w3 * x; acc[h][4] += w4 * x;
          }
        }
      }
  float x[D_];
#pragma unroll
  for (int h = 0; h < 4; ++h)
#pragma unroll
    for (int c = 0; c < 5; ++c) x[h * 5 + c] = acc[h][c];
  float q[D_], k[D_], v[D_];
#pragma unroll
  for (int j = 0; j < D_; ++j) { q[j] = 0.f; k[j] = 0.f; v[j] = 0.f; }
#pragma unroll
  for (int i = 0; i < D_; ++i) {
#pragma unroll
    for (int j = 0; j < D_; ++j) {
      q[j] += x[i] * qw[i * D_ + j];
      k[j] += x[i] * kw[i * D_ + j];
      v[j] += x[i] * vw[i * D_ + j];
    }
  }
  const float sc = 0.22360679774997896f;  // 1/sqrt(20)
  ushort_t qt[32], kt[32];
#pragma unroll
  for (int j = 0; j < D_; ++j) { qt[j] = f2bf(q[j] * sc); kt[j] = f2bf(k[j]); }
#pragma unroll
  for (int j = D_; j < 32; ++j) { qt[j] = 0; kt[j] = 0; }
  int4* qd = (int4*)(Qb + (size_t)r * 32);
  int4* kd = (int4*)(Kb + (size_t)r * 32);
#pragma unroll
  for (int j = 0; j < 4; ++j) {
    qd[j] = *(const int4*)(qt + 8 * j);
    kd[j] = *(const int4*)(kt + 8 * j);
  }
  ushort_t* vbase = Vt + ((size_t)b * 32) * 1024 + wo;
#pragma unroll
  for (int d = 0; d < D_; ++d) vbase[d * 1024] = f2bf(v[d]);
}

// ---------------- causal attention via bf16 MFMA (register-resident P) ----
// S^T = mfma_16x16x32(Kfrag, Qfrag): lane (quad,n): S^T[t=quad*4+r][q=n].
// After exp/mask, that register layout IS the B-operand of
// mfma_f32_16x16x16_bf16 (k=quad*4+j). PV: O^T = mfma16(V^T-frag, P^T, O^T),
// A-frag = V^T[d=n][t=quad*4+j] (b64 from vts). No P LDS traffic at all.
// l: per-lane partial over its 4 t's, reduced across quads (shfl 16,32).
// FUSE=true : epilogue projects O rows -> next layer's Qb2/Kb2/Vt2.
// FUSE=false: epilogue computes dense1 partial -> part2[b][strip][10].
#define TT_ 128
template <bool FUSE>
__global__ __launch_bounds__(256) void attn_kernel(
    const ushort_t* __restrict__ Qb, const ushort_t* __restrict__ Kb,
    const ushort_t* __restrict__ Vt,
    const float* __restrict__ Kw2, const float* __restrict__ Qw2,
    const float* __restrict__ Vw2,
    ushort_t* __restrict__ Qb2, ushort_t* __restrict__ Kb2,
    ushort_t* __restrict__ Vt2,
    const float* __restrict__ W1T,   // !FUSE: [10,20480]
    float* __restrict__ part2) {     // !FUSE: [64,16,10]
  const int b     = blockIdx.y;
  const int strip = (blockIdx.x + 4 * (blockIdx.y >> 4)) & 15;
  const int q0    = strip * 64;
  const int tid   = threadIdx.x;
  const int w     = tid >> 6;             // wave 0..3
  const int lane  = tid & 63;
  const int n     = lane & 15;
  const int quad  = lane >> 4;
  const int qbase = q0 + 16 * w;
  const int qg    = qbase + n;            // this lane's q column
  __shared__ ushort_t kts[128 * 40];      // K tile, row stride 40 us (80 B)
  __shared__ ushort_t vts[32 * 136];      // V^T tile, row stride 136 us (272 B)
  // FUSE:  [0..1200) proj weights K|Q|V, [1200..2480) ox (4x320)
  // !FUSE: [0..1280) ox flat, [1280..3840) red (256x10)
  __shared__ float extraf[FUSE ? 2480 : 3840];
  if (FUSE) {
    float tmp[5];
#pragma unroll
    for (int u = 0; u < 5; ++u) {
      int j = tid + u * 256;
      if (j < 1200) {
        int m = j / 400, oo = j - m * 400;
        tmp[u] = (m == 0) ? Kw2[oo] : (m == 1) ? Qw2[oo] : Vw2[oo];
      }
    }
#pragma unroll
    for (int u = 0; u < 5; ++u) {
      int j = tid + u * 256;
      if (j < 1200) extraf[j] = tmp[u];
    }
  }
  const ushort_t* KbB = Kb + (size_t)b * 1024 * 32;
  const ushort_t* VtB = Vt + (size_t)b * 32 * 1024;
  short8_t qfrag = *(const short8_t*)(Qb + ((size_t)(b * 1024 + qbase + n)) * 32 + quad * 8);
  f32x4_t oA = {0.f, 0.f, 0.f, 0.f};      // O^T[d=quad*4+r][q=n]
  f32x4_t oB = {0.f, 0.f, 0.f, 0.f};      // O^T[d=16+quad*4+r][q=n] (quad0 valid)
  float lsum = 0.f;
  const f32x4_t zero = {0.f, 0.f, 0.f, 0.f};
  const int nt = q0 + 64;                 // block-uniform staging bound
  for (int t0 = 0; t0 < nt; t0 += TT_) {
    __syncthreads();
    for (int i = tid; i < 512; i += 256) {
      int row = i >> 2, qc = i & 3;
      *(int4*)(kts + row * 40 + qc * 8) =
          *(const int4*)(KbB + (size_t)(t0 + row) * 32 + qc * 8);
    }
    for (int i = tid; i < 320; i += 256) {
      int row = i >> 4, cc = i & 15;
      *(int4*)(vts + row * 136 + cc * 8) =
          *(const int4*)(VtB + (size_t)row * 1024 + t0 + cc * 8);
    }
    __syncthreads();
    // preload K A-frags for all 8 16-t blocks (no LDS dep in compute loop)
    short8_t kf[8];
#pragma unroll
    for (int hc = 0; hc < 8; ++hc)
      kf[hc] = *(const short8_t*)(kts + (hc * 16 + n) * 40 + quad * 8);
#pragma unroll
    for (int hc = 0; hc < 8; ++hc) {
      const int tg = t0 + hc * 16 + quad * 4;     // global t of r=0
      // S^T[t][q]: A = K rows (m=t), B = Q (n=q). Same registers, swapped.
      f32x4_t s = __builtin_amdgcn_mfma_f32_16x16x32_bf16(kf[hc], qfrag, zero, 0, 0, 0);
      ushort_t pk4[4];
#pragma unroll
      for (int r = 0; r < 4; ++r) {
        float p = (tg + r <= qg) ? __expf(s[r]) : 0.f;
        ushort_t h = f2bf(p);
        lsum += bf2f(h);                  // consistent with bf16 P used in PV
        pk4[r] = h;
      }
      short4_t pfrag = *(const short4_t*)pk4;     // B16-frag: k=quad*4+j, n=q
      short4_t vlo = *(const short4_t*)(vts + n * 136 + hc * 16 + quad * 4);
      short4_t vhi = *(const short4_t*)(vts + (16 + n) * 136 + hc * 16 + quad * 4);
      oA = __builtin_amdgcn_mfma_f32_16x16x16bf16_1k(vlo, pfrag, oA, 0, 0, 0);
      oB = __builtin_amdgcn_mfma_f32_16x16x16bf16_1k(vhi, pfrag, oB, 0, 0, 0);
    }
  }
  // l[q=n]: reduce partial sums across the 4 quads (lanes n, n+16, n+32, n+48)
  float l = lsum;
  l += __shfl_xor(l, 16, 64);
  l += __shfl_xor(l, 32, 64);
  const float inv = 1.f / l;
  if (FUSE) {
    float* pw  = extraf;
    float* oxw = extraf + 1200 + w * 320;
#pragma unroll
    for (int r = 0; r < 4; ++r) oxw[n * 20 + quad * 4 + r] = oA[r] * inv;
    if (quad == 0) {
#pragma unroll
      for (int r = 0; r < 4; ++r) oxw[n * 20 + 16 + r] = oB[r] * inv;
    }
    __asm__ volatile("s_waitcnt lgkmcnt(0)" ::: "memory");  // wave-sync LDS RAW
    const int row  = lane >> 2;     // 0..15
    const int part = lane & 3;      // cols 5*part .. 5*part+4
    float x[D_];
#pragma unroll
    for (int i = 0; i < D_; ++i) x[i] = oxw[row * 20 + i];
    float qv[5], kv[5], vv[5];
#pragma unroll
    for (int jj = 0; jj < 5; ++jj) { qv[jj] = 0.f; kv[jj] = 0.f; vv[jj] = 0.f; }
#pragma unroll
    for (int i = 0; i < D_; ++i) {
      const float xi = x[i];
#pragma unroll
      for (int jj = 0; jj < 5; ++jj) {
        const int j = 5 * part + jj;
        kv[jj] += xi * pw[i * 20 + j];          // K block
        qv[jj] += xi * pw[400 + i * 20 + j];    // Q block
        vv[jj] += xi * pw[800 + i * 20 + j];    // V block
      }
    }
    const float sc = 0.22360679774997896f;
    const int rg = b * 1024 + qbase + row;
    const int s  = rg & 1023;
#pragma unroll
    for (int jj = 0; jj < 5; ++jj) {
      const int j = 5 * part + jj;
      Kb2[(size_t)rg * 32 + j] = f2bf(kv[jj]);
      Qb2[(size_t)rg * 32 + j] = f2bf(qv[jj] * sc);
      Vt2[(size_t)b * 32768 + (size_t)j * 1024 + s] = f2bf(vv[jj]);
    }
    if (part == 0) {
#pragma unroll
      for (int u = 0; u < 6; ++u)
        *(unsigned*)(Kb2 + (size_t)rg * 32 + 20 + 2 * u) = 0u;
    } else if (part == 1) {
#pragma unroll
      for (int u = 0; u < 6; ++u)
        *(unsigned*)(Qb2 + (size_t)rg * 32 + 20 + 2 * u) = 0u;
    }
  } else {
    // ---- fused dense1 partial over this block's 64 rows ----
    float* oxflat = extraf;              // [1280] = X[b, q0*20 .. q0*20+1280)
    float* oxw    = oxflat + w * 320;    // this wave's 16 rows (contiguous)
    float* red    = extraf + 1280;       // [256][10]
#pragma unroll
    for (int r = 0; r < 4; ++r) oxw[n * 20 + quad * 4 + r] = oA[r] * inv;
    if (quad == 0) {
#pragma unroll
      for (int r = 0; r < 4; ++r) oxw[n * 20 + 16 + r] = oB[r] * inv;
    }
    __syncthreads();                     // all waves' ox visible
    float acc[10];
#pragma unroll
    for (int j = 0; j < 10; ++j) acc[j] = 0.f;
    const float* wb = W1T;               // [10][20480]
    const int base = q0 * 20;
#pragma unroll
    for (int k = 0; k < 5; ++k) {
      const int il = tid + 256 * k;
      const float xv = oxflat[il];
#pragma unroll
      for (int j = 0; j < 10; ++j)
        acc[j] += xv * wb[(size_t)j * 20480 + base + il];  // lane-coalesced
    }
#pragma unroll
    for (int j = 0; j < 10; ++j) red[tid * 10 + j] = acc[j];
    __syncthreads();
    for (int off = 128; off > 0; off >>= 1) {
      if (tid < off) {
#pragma unroll
        for (int j = 0; j < 10; ++j) red[tid * 10 + j] += red[(tid + off) * 10 + j];
      }
      __syncthreads();
    }
    if (tid < 10) part2[((b << 4) + strip) * 10 + tid] = red[tid];
  }
}

// ---------------- dense head: combine strips + dense2/3 ----------------
__global__ __launch_bounds__(64) void dense_final(
    const float* __restrict__ part2,   // [64,16,10], strip-ordered
    const float* __restrict__ B1,
    const float* __restrict__ W2, const float* __restrict__ B2,
    const float* __restrict__ W3, const float* __restrict__ B3,
    float* __restrict__ out) {
  const int b = blockIdx.x;
  __shared__ float y1[10], y2[10];
  if (threadIdx.x < 10) {
    int j = threadIdx.x;
    float s = 0.f;
#pragma unroll
    for (int st = 0; st < 16; ++st) s += part2[((b << 4) + st) * 10 + j];
    y1[j] = s + B1[j];
  }
  __syncthreads();
  if (threadIdx.x < 10) {
    int j = threadIdx.x;
    float s = B2[j];
#pragma unroll
    for (int i = 0; i < 10; ++i) s += y1[i] * W2[i * 10 + j];
    y2[j] = s;
  }
  __syncthreads();
  if (threadIdx.x < 10) {
    int j = threadIdx.x;
    float s = B3[j];
#pragma unroll
    for (int i = 0; i < 10; ++i) s += y2[i] * W3[i * 10 + j];
    out[b * 10 + j] = s;
  }
}

extern "C" void kernel_launch(void* const* d_in, const int* in_sizes, int n_in,
                              void* d_out, int out_size, void* d_ws, size_t ws_size,
                              hipStream_t stream) {
  const int*   inp = (const int*)d_in[0];
  const float* cw1 = (const float*)d_in[1];
  const float* cb1 = (const float*)d_in[2];
  const float* cw2 = (const float*)d_in[3];
  const float* cb2 = (const float*)d_in[4];
  const float* cw3 = (const float*)d_in[5];
  const float* cb3 = (const float*)d_in[6];
  const float* a1K = (const float*)d_in[7];
  const float* a1Q = (const float*)d_in[8];
  const float* a1V = (const float*)d_in[9];
  const float* a2K = (const float*)d_in[10];
  const float* a2Q = (const float*)d_in[11];
  const float* a2V = (const float*)d_in[12];
  const float* a3K = (const float*)d_in[13];
  const float* a3Q = (const float*)d_in[14];
  const float* a3V = (const float*)d_in[15];
  const float* dw1 = (const float*)d_in[16];
  const float* db1 = (const float*)d_in[17];
  const float* dw2 = (const float*)d_in[18];
  const float* db2 = (const float*)d_in[19];
  const float* dw3 = (const float*)d_in[20];
  const float* db3 = (const float*)d_in[21];
  float* outp = (float*)d_out;

  // workspace layout (float units)
  float* wsf = (float*)d_ws;
  ushort_t* qbA  = (ushort_t*)(wsf);            // [65536][32] bf16  [0 .. 1,048,576)
  ushort_t* kbA  = (ushort_t*)(wsf + 1048576);  //                   [1,048,576 .. 2,097,152)
  ushort_t* vtA  = (ushort_t*)(wsf + 2097152);  // [B,32,S]          [2,097,152 .. 3,145,728)
  float*    part2= wsf + 4456448;               // [64,16,10]        [4,456,448 .. 4,466,688)
  float*    w1t  = wsf + 4466688;               // [10,20480]        ends 4,671,488
  ushort_t* qbB  = (ushort_t*)(wsf + 4671488);  // ends 5,195,776
  ushort_t* kbB  = (ushort_t*)(wsf + 5712384);  // B-buffers overlap dead c2 region
  ushort_t* vtB  = (ushort_t*)(wsf + 6760960);  //   (c2 consumed before attn1 writes B)
  float*    c2   = wsf + 5242880;               // [B,4,2048,5]      [5,242,880 .. 7,864,320)

  conv12_kernel<<<512, 256, 0, stream>>>(inp, cw1, cb1, cw2, cb2, c2, dw1, w1t);

  conv3_proj_kernel<<<256, 256, 0, stream>>>(c2, cw3, cb3, a1K, a1Q, a1V, qbA, kbA, vtA);
  // attn1: reads A, fused proj(layer2) -> B
  attn_kernel<true><<<dim3(16, 64), 256, 0, stream>>>(
      qbA, kbA, vtA, a2K, a2Q, a2V, qbB, kbB, vtB, nullptr, nullptr);
  // attn2: reads B, fused proj(layer3) -> A
  attn_kernel<true><<<dim3(16, 64), 256, 0, stream>>>(
      qbB, kbB, vtB, a3K, a3Q, a3V, qbA, kbA, vtA, nullptr, nullptr);
  // attn3: reads A, fused dense1 partial -> part2
  attn_kernel<false><<<dim3(16, 64), 256, 0, stream>>>(
      qbA, kbA, vtA, nullptr, nullptr, nullptr, nullptr, nullptr, nullptr,
      w1t, part2);

  dense_final<<<64, 64, 0, stream>>>(part2, db1, dw2, db2, dw3, db3, outp);
}

// Round 19
// 215.540 us; speedup vs baseline: 1.1184x; 1.0101x over previous
//
#include <hip/hip_runtime.h>
#include <hip/hip_bf16.h>

// Model: one_hot -> 3x Conv2D(5,(4,4),(1,2),SAME) -> [B,S=1024,D=20]
//        -> 3x causal self-attention -> flatten -> 3x Dense(10)
// B=64, L=8192, S=1024, D=20.
// R12: conv1 fused into conv2. R13: conv3 fused into proj layer-1.
// R15: K-frag preload + full chunk unroll. R17: 6-launch consolidation.
// R18: register-resident P (S^T = mfma(K,Q); C/D layout == B-operand layout
//      of mfma_16x16x16 -> PV directly from registers) — -21 us.
// R19: strip swizzle rebalanced: co-resident blocks (same bx, by>>4 = g..g+3)
//      get strips {bx, 15-bx, bx+4, 11-bx} (per-g bijections) whose weight
//      sum is 34 for EVERY bx -> CU makespan 1.0x (was {bx,bx+4,bx+8,bx+12},
//      load 28..40, 1.18x). Pure scheduling relabel — bit-identical output.

#define B_ 64
#define L_ 8192
#define S_ 1024
#define D_ 20

typedef unsigned short ushort_t;
typedef __attribute__((ext_vector_type(8))) short short8_t;  // 8 bf16 (4 VGPRs)
typedef __attribute__((ext_vector_type(4))) short short4_t;  // 4 bf16 (2 VGPRs)
typedef __attribute__((ext_vector_type(4))) float f32x4_t;   // MFMA C/D

__device__ __forceinline__ ushort_t f2bf(float f) {          // RNE fp32->bf16
  unsigned u = __float_as_uint(f);
  return (ushort_t)((u + 0x7fffu + ((u >> 16) & 1u)) >> 16);
}
__device__ __forceinline__ float bf2f(ushort_t h) {
  return __uint_as_float(((unsigned)h) << 16);
}

// ---------------- fused conv1+conv2 (+ W1 transpose tail) ----------------
__global__ __launch_bounds__(256) void conv12_kernel(
    const int* __restrict__ inp,
    const float* __restrict__ W1c, const float* __restrict__ B1c,
    const float* __restrict__ W2c, const float* __restrict__ B2c,
    float* __restrict__ out,                      // c2 [B,4,2048,5]
    const float* __restrict__ W1d,                // dense W1 [20480,10]
    float* __restrict__ W1T) {                    // [10,20480]
  __shared__ float w1s[80], b1s[5], w2s[400], b2s[5];
  for (int j = threadIdx.x; j < 400; j += 256) w2s[j] = W2c[j];
  if (threadIdx.x < 80)      w1s[threadIdx.x]      = W1c[threadIdx.x];
  else if (threadIdx.x < 85) b1s[threadIdx.x - 80] = B1c[threadIdx.x - 80];
  else if (threadIdx.x < 90) b2s[threadIdx.x - 85] = B2c[threadIdx.x - 85];
  __syncthreads();
  const int idx = blockIdx.x * 256 + threadIdx.x;  // 131072 total
  const int b  = idx >> 11;
  const int wo = idx & 2047;
  const int* ib = inp + (size_t)b * L_;
  int iv[10];
#pragma unroll
  for (int t = 0; t < 10; ++t) {
    int g = 4 * wo - 3 + t;
    iv[t] = (g >= 0 && g < L_) ? ib[g] : -100;   // sentinel: no kh matches
  }
  float val[4][4][5];                            // [hi][pos][ci]
#pragma unroll
  for (int pos = 0; pos < 4; ++pos) {
    const int w1 = 2 * wo - 1 + pos;
    const bool okp = (w1 >= 0 && w1 < 4096);     // conv2 SAME padding -> 0
#pragma unroll
    for (int hi = 0; hi < 4; ++hi)
#pragma unroll
      for (int ci = 0; ci < 5; ++ci) val[hi][pos][ci] = okp ? b1s[ci] : 0.f;
    if (okp) {
#pragma unroll
      for (int kw = 0; kw < 4; ++kw) {
        const int gw = 2 * w1 - 1 + kw;
        if (gw >= 0 && gw < L_) {
          const int v = iv[2 * pos + kw];
#pragma unroll
          for (int hi = 0; hi < 4; ++hi) {
            const int kh = v - hi + 1;
            if (kh >= 0 && kh < 4) {
#pragma unroll
              for (int ci = 0; ci < 5; ++ci)
                val[hi][pos][ci] += w1s[(kh * 4 + kw) * 5 + ci];
            }
          }
        }
      }
    }
  }
  float acc[4][5];
#pragma unroll
  for (int h = 0; h < 4; ++h)
#pragma unroll
    for (int c = 0; c < 5; ++c) acc[h][c] = b2s[c];
#pragma unroll
  for (int kh = 0; kh < 4; ++kh)
#pragma unroll
    for (int kw = 0; kw < 4; ++kw)
#pragma unroll
      for (int ci = 0; ci < 5; ++ci) {
        const float* wp = w2s + ((kh * 4 + kw) * 5 + ci) * 5;
        float w0 = wp[0], w1v = wp[1], w2v = wp[2], w3 = wp[3], w4 = wp[4];
#pragma unroll
        for (int h = 0; h < 4; ++h) {
          int hi = h - 1 + kh;
          if (hi >= 0 && hi < 4) {
            float x = val[hi][kw][ci];
            acc[h][0] += w0 * x;  acc[h][1] += w1v * x; acc[h][2] += w2v * x;
            acc[h][3] += w3 * x;  acc[h][4] += w4 * x;
          }
        }
      }
  float* ob = out + (size_t)b * 4 * 2048 * 5;
#pragma unroll
  for (int h = 0; h < 4; ++h)
#pragma unroll
    for (int c = 0; c < 5; ++c) ob[(h * 2048 + wo) * 5 + c] = acc[h][c];
  // ---- tail: W1 transpose (grid-stride over 204800 elements) ----
  for (int j = idx; j < 204800; j += 131072) {
    int col = j / 20480, i2 = j - col * 20480;
    W1T[j] = W1d[i2 * 10 + col];
  }
}

// ---------------- fused conv3 + proj (layer 1) ----------------
__global__ __launch_bounds__(256) void conv3_proj_kernel(
    const float* __restrict__ in,                 // c2 [B,4,2048,5]
    const float* __restrict__ W,  const float* __restrict__ Bi,
    const float* __restrict__ Kw, const float* __restrict__ Qw,
    const float* __restrict__ Vw,
    ushort_t* __restrict__ Qb, ushort_t* __restrict__ Kb,
    ushort_t* __restrict__ Vt) {
  constexpr int WIN = 2048;
  __shared__ float ws[400], bs[5];
  __shared__ float kw[400], qw[400], vw[400];
  for (int j = threadIdx.x; j < 400; j += 256) {
    ws[j] = W[j]; kw[j] = Kw[j]; qw[j] = Qw[j]; vw[j] = Vw[j];
  }
  if (threadIdx.x < 5) bs[threadIdx.x] = Bi[threadIdx.x];
  __syncthreads();
  const int r  = blockIdx.x * 256 + threadIdx.x;  // row in [0, 65536)
  const int b  = r >> 10;
  const int wo = r & 1023;
  float val[4][4][5];
#pragma unroll
  for (int hi = 0; hi < 4; ++hi) {
    const float* ir = in + ((size_t)b * 4 + hi) * WIN * 5;
#pragma unroll
    for (int kwp = 0; kwp < 4; ++kwp) {
      int wi = 2 * wo - 1 + kwp;
      bool ok = (wi >= 0 && wi < WIN);
#pragma unroll
      for (int ci = 0; ci < 5; ++ci) val[hi][kwp][ci] = ok ? ir[wi * 5 + ci] : 0.f;
    }
  }
  float acc[4][5];
#pragma unroll
  for (int h = 0; h < 4; ++h)
#pragma unroll
    for (int c = 0; c < 5; ++c) acc[h][c] = bs[c];
#pragma unroll
  for (int kh = 0; kh < 4; ++kh)
#pragma unroll
    for (int kwp = 0; kwp < 4; ++kwp)
#pragma unroll
      for (int ci = 0; ci < 5; ++ci) {
        const float* wp = ws + ((kh * 4 + kwp) * 5 + ci) * 5;
        float w0 = wp[0], w1 = wp[1], w2 = wp[2], w3 = wp[3], w4 = wp[4];
#pragma unroll
        for (int h = 0; h < 4; ++h) {
          int hi = h - 1 + kh;
          if (hi >= 0 && hi < 4) {
            float x = val[hi][kwp][ci];
            acc[h][0] += w0 * x; acc[h][1] += w1 * x; acc[h][2] += w2 * x;
            acc[h][3] += w3 * x; acc[h][4] += w4 * x;
          }
        }
      }
  float x[D_];
#pragma unroll
  for (int h = 0; h < 4; ++h)
#pragma unroll
    for (int c = 0; c < 5; ++c) x[h * 5 + c] = acc[h][c];
  float q[D_], k[D_], v[D_];
#pragma unroll
  for (int j = 0; j < D_; ++j) { q[j] = 0.f; k[j] = 0.f; v[j] = 0.f; }
#pragma unroll
  for (int i = 0; i < D_; ++i) {
#pragma unroll
    for (int j = 0; j < D_; ++j) {
      q[j] += x[i] * qw[i * D_ + j];
      k[j] += x[i] * kw[i * D_ + j];
      v[j] += x[i] * vw[i * D_ + j];
    }
  }
  const float sc = 0.22360679774997896f;  // 1/sqrt(20)
  ushort_t qt[32], kt[32];
#pragma unroll
  for (int j = 0; j < D_; ++j) { qt[j] = f2bf(q[j] * sc); kt[j] = f2bf(k[j]); }
#pragma unroll
  for (int j = D_; j < 32; ++j) { qt[j] = 0; kt[j] = 0; }
  int4* qd = (int4*)(Qb + (size_t)r * 32);
  int4* kd = (int4*)(Kb + (size_t)r * 32);
#pragma unroll
  for (int j = 0; j < 4; ++j) {
    qd[j] = *(const int4*)(qt + 8 * j);
    kd[j] = *(const int4*)(kt + 8 * j);
  }
  ushort_t* vbase = Vt + ((size_t)b * 32) * 1024 + wo;
#pragma unroll
  for (int d = 0; d < D_; ++d) vbase[d * 1024] = f2bf(v[d]);
}

// ---------------- causal attention via bf16 MFMA (register-resident P) ----
// S^T = mfma_16x16x32(Kfrag, Qfrag): lane (quad,n): S^T[t=quad*4+r][q=n].
// After exp/mask, that register layout IS the B-operand of
// mfma_f32_16x16x16_bf16 (k=quad*4+j). PV: O^T = mfma16(V^T-frag, P^T, O^T),
// A-frag = V^T[d=n][t=quad*4+j] (b64 from vts). No P LDS traffic at all.
// l: per-lane partial over its 4 t's, reduced across quads (shfl 16,32).
// R19 strip swizzle: per-g bijection with constant co-resident weight sum.
// FUSE=true : epilogue projects O rows -> next layer's Qb2/Kb2/Vt2.
// FUSE=false: epilogue computes dense1 partial -> part2[b][strip][10].
#define TT_ 128
template <bool FUSE>
__global__ __launch_bounds__(256) void attn_kernel(
    const ushort_t* __restrict__ Qb, const ushort_t* __restrict__ Kb,
    const ushort_t* __restrict__ Vt,
    const float* __restrict__ Kw2, const float* __restrict__ Qw2,
    const float* __restrict__ Vw2,
    ushort_t* __restrict__ Qb2, ushort_t* __restrict__ Kb2,
    ushort_t* __restrict__ Vt2,
    const float* __restrict__ W1T,   // !FUSE: [10,20480]
    float* __restrict__ part2) {     // !FUSE: [64,16,10]
  const int b     = blockIdx.y;
  // balanced strip swizzle: co-residents (same bx, g..g+3) weight-sum = 34
  const int g     = (blockIdx.y >> 4) & 3;
  const int off   = 4 * (g >> 1);
  const int strip = (g & 1) ? ((15 - off - blockIdx.x) & 15)
                            : (((int)blockIdx.x + off) & 15);
  const int q0    = strip * 64;
  const int tid   = threadIdx.x;
  const int w     = tid >> 6;             // wave 0..3
  const int lane  = tid & 63;
  const int n     = lane & 15;
  const int quad  = lane >> 4;
  const int qbase = q0 + 16 * w;
  const int qg    = qbase + n;            // this lane's q column
  __shared__ ushort_t kts[128 * 40];      // K tile, row stride 40 us (80 B)
  __shared__ ushort_t vts[32 * 136];      // V^T tile, row stride 136 us (272 B)
  // FUSE:  [0..1200) proj weights K|Q|V, [1200..2480) ox (4x320)
  // !FUSE: [0..1280) ox flat, [1280..3840) red (256x10)
  __shared__ float extraf[FUSE ? 2480 : 3840];
  if (FUSE) {
    float tmp[5];
#pragma unroll
    for (int u = 0; u < 5; ++u) {
      int j = tid + u * 256;
      if (j < 1200) {
        int m = j / 400, oo = j - m * 400;
        tmp[u] = (m == 0) ? Kw2[oo] : (m == 1) ? Qw2[oo] : Vw2[oo];
      }
    }
#pragma unroll
    for (int u = 0; u < 5; ++u) {
      int j = tid + u * 256;
      if (j < 1200) extraf[j] = tmp[u];
    }
  }
  const ushort_t* KbB = Kb + (size_t)b * 1024 * 32;
  const ushort_t* VtB = Vt + (size_t)b * 32 * 1024;
  short8_t qfrag = *(const short8_t*)(Qb + ((size_t)(b * 1024 + qbase + n)) * 32 + quad * 8);
  f32x4_t oA = {0.f, 0.f, 0.f, 0.f};      // O^T[d=quad*4+r][q=n]
  f32x4_t oB = {0.f, 0.f, 0.f, 0.f};      // O^T[d=16+quad*4+r][q=n] (quad0 valid)
  float lsum = 0.f;
  const f32x4_t zero = {0.f, 0.f, 0.f, 0.f};
  const int nt = q0 + 64;                 // block-uniform staging bound
  for (int t0 = 0; t0 < nt; t0 += TT_) {
    __syncthreads();
    for (int i = tid; i < 512; i += 256) {
      int row = i >> 2, qc = i & 3;
      *(int4*)(kts + row * 40 + qc * 8) =
          *(const int4*)(KbB + (size_t)(t0 + row) * 32 + qc * 8);
    }
    for (int i = tid; i < 320; i += 256) {
      int row = i >> 4, cc = i & 15;
      *(int4*)(vts + row * 136 + cc * 8) =
          *(const int4*)(VtB + (size_t)row * 1024 + t0 + cc * 8);
    }
    __syncthreads();
    // preload K A-frags for all 8 16-t blocks (no LDS dep in compute loop)
    short8_t kf[8];
#pragma unroll
    for (int hc = 0; hc < 8; ++hc)
      kf[hc] = *(const short8_t*)(kts + (hc * 16 + n) * 40 + quad * 8);
#pragma unroll
    for (int hc = 0; hc < 8; ++hc) {
      const int tg = t0 + hc * 16 + quad * 4;     // global t of r=0
      // S^T[t][q]: A = K rows (m=t), B = Q (n=q). Same registers, swapped.
      f32x4_t s = __builtin_amdgcn_mfma_f32_16x16x32_bf16(kf[hc], qfrag, zero, 0, 0, 0);
      ushort_t pk4[4];
#pragma unroll
      for (int r = 0; r < 4; ++r) {
        float p = (tg + r <= qg) ? __expf(s[r]) : 0.f;
        ushort_t h = f2bf(p);
        lsum += bf2f(h);                  // consistent with bf16 P used in PV
        pk4[r] = h;
      }
      short4_t pfrag = *(const short4_t*)pk4;     // B16-frag: k=quad*4+j, n=q
      short4_t vlo = *(const short4_t*)(vts + n * 136 + hc * 16 + quad * 4);
      short4_t vhi = *(const short4_t*)(vts + (16 + n) * 136 + hc * 16 + quad * 4);
      oA = __builtin_amdgcn_mfma_f32_16x16x16bf16_1k(vlo, pfrag, oA, 0, 0, 0);
      oB = __builtin_amdgcn_mfma_f32_16x16x16bf16_1k(vhi, pfrag, oB, 0, 0, 0);
    }
  }
  // l[q=n]: reduce partial sums across the 4 quads (lanes n, n+16, n+32, n+48)
  float l = lsum;
  l += __shfl_xor(l, 16, 64);
  l += __shfl_xor(l, 32, 64);
  const float inv = 1.f / l;
  if (FUSE) {
    float* pw  = extraf;
    float* oxw = extraf + 1200 + w * 320;
#pragma unroll
    for (int r = 0; r < 4; ++r) oxw[n * 20 + quad * 4 + r] = oA[r] * inv;
    if (quad == 0) {
#pragma unroll
      for (int r = 0; r < 4; ++r) oxw[n * 20 + 16 + r] = oB[r] * inv;
    }
    __asm__ volatile("s_waitcnt lgkmcnt(0)" ::: "memory");  // wave-sync LDS RAW
    const int row  = lane >> 2;     // 0..15
    const int part = lane & 3;      // cols 5*part .. 5*part+4
    float x[D_];
#pragma unroll
    for (int i = 0; i < D_; ++i) x[i] = oxw[row * 20 + i];
    float qv[5], kv[5], vv[5];
#pragma unroll
    for (int jj = 0; jj < 5; ++jj) { qv[jj] = 0.f; kv[jj] = 0.f; vv[jj] = 0.f; }
#pragma unroll
    for (int i = 0; i < D_; ++i) {
      const float xi = x[i];
#pragma unroll
      for (int jj = 0; jj < 5; ++jj) {
        const int j = 5 * part + jj;
        kv[jj] += xi * pw[i * 20 + j];          // K block
        qv[jj] += xi * pw[400 + i * 20 + j];    // Q block
        vv[jj] += xi * pw[800 + i * 20 + j];    // V block
      }
    }
    const float sc = 0.22360679774997896f;
    const int rg = b * 1024 + qbase + row;
    const int s  = rg & 1023;
#pragma unroll
    for (int jj = 0; jj < 5; ++jj) {
      const int j = 5 * part + jj;
      Kb2[(size_t)rg * 32 + j] = f2bf(kv[jj]);
      Qb2[(size_t)rg * 32 + j] = f2bf(qv[jj] * sc);
      Vt2[(size_t)b * 32768 + (size_t)j * 1024 + s] = f2bf(vv[jj]);
    }
    if (part == 0) {
#pragma unroll
      for (int u = 0; u < 6; ++u)
        *(unsigned*)(Kb2 + (size_t)rg * 32 + 20 + 2 * u) = 0u;
    } else if (part == 1) {
#pragma unroll
      for (int u = 0; u < 6; ++u)
        *(unsigned*)(Qb2 + (size_t)rg * 32 + 20 + 2 * u) = 0u;
    }
  } else {
    // ---- fused dense1 partial over this block's 64 rows ----
    float* oxflat = extraf;              // [1280] = X[b, q0*20 .. q0*20+1280)
    float* oxw    = oxflat + w * 320;    // this wave's 16 rows (contiguous)
    float* red    = extraf + 1280;       // [256][10]
#pragma unroll
    for (int r = 0; r < 4; ++r) oxw[n * 20 + quad * 4 + r] = oA[r] * inv;
    if (quad == 0) {
#pragma unroll
      for (int r = 0; r < 4; ++r) oxw[n * 20 + 16 + r] = oB[r] * inv;
    }
    __syncthreads();                     // all waves' ox visible
    float acc[10];
#pragma unroll
    for (int j = 0; j < 10; ++j) acc[j] = 0.f;
    const float* wb = W1T;               // [10][20480]
    const int base = q0 * 20;
#pragma unroll
    for (int k = 0; k < 5; ++k) {
      const int il = tid + 256 * k;
      const float xv = oxflat[il];
#pragma unroll
      for (int j = 0; j < 10; ++j)
        acc[j] += xv * wb[(size_t)j * 20480 + base + il];  // lane-coalesced
    }
#pragma unroll
    for (int j = 0; j < 10; ++j) red[tid * 10 + j] = acc[j];
    __syncthreads();
    for (int off2 = 128; off2 > 0; off2 >>= 1) {
      if (tid < off2) {
#pragma unroll
        for (int j = 0; j < 10; ++j) red[tid * 10 + j] += red[(tid + off2) * 10 + j];
      }
      __syncthreads();
    }
    if (tid < 10) part2[((b << 4) + strip) * 10 + tid] = red[tid];
  }
}

// ---------------- dense head: combine strips + dense2/3 ----------------
__global__ __launch_bounds__(64) void dense_final(
    const float* __restrict__ part2,   // [64,16,10], strip-ordered
    const float* __restrict__ B1,
    const float* __restrict__ W2, const float* __restrict__ B2,
    const float* __restrict__ W3, const float* __restrict__ B3,
    float* __restrict__ out) {
  const int b = blockIdx.x;
  __shared__ float y1[10], y2[10];
  if (threadIdx.x < 10) {
    int j = threadIdx.x;
    float s = 0.f;
#pragma unroll
    for (int st = 0; st < 16; ++st) s += part2[((b << 4) + st) * 10 + j];
    y1[j] = s + B1[j];
  }
  __syncthreads();
  if (threadIdx.x < 10) {
    int j = threadIdx.x;
    float s = B2[j];
#pragma unroll
    for (int i = 0; i < 10; ++i) s += y1[i] * W2[i * 10 + j];
    y2[j] = s;
  }
  __syncthreads();
  if (threadIdx.x < 10) {
    int j = threadIdx.x;
    float s = B3[j];
#pragma unroll
    for (int i = 0; i < 10; ++i) s += y2[i] * W3[i * 10 + j];
    out[b * 10 + j] = s;
  }
}

extern "C" void kernel_launch(void* const* d_in, const int* in_sizes, int n_in,
                              void* d_out, int out_size, void* d_ws, size_t ws_size,
                              hipStream_t stream) {
  const int*   inp = (const int*)d_in[0];
  const float* cw1 = (const float*)d_in[1];
  const float* cb1 = (const float*)d_in[2];
  const float* cw2 = (const float*)d_in[3];
  const float* cb2 = (const float*)d_in[4];
  const float* cw3 = (const float*)d_in[5];
  const float* cb3 = (const float*)d_in[6];
  const float* a1K = (const float*)d_in[7];
  const float* a1Q = (const float*)d_in[8];
  const float* a1V = (const float*)d_in[9];
  const float* a2K = (const float*)d_in[10];
  const float* a2Q = (const float*)d_in[11];
  const float* a2V = (const float*)d_in[12];
  const float* a3K = (const float*)d_in[13];
  const float* a3Q = (const float*)d_in[14];
  const float* a3V = (const float*)d_in[15];
  const float* dw1 = (const float*)d_in[16];
  const float* db1 = (const float*)d_in[17];
  const float* dw2 = (const float*)d_in[18];
  const float* db2 = (const float*)d_in[19];
  const float* dw3 = (const float*)d_in[20];
  const float* db3 = (const float*)d_in[21];
  float* outp = (float*)d_out;

  // workspace layout (float units)
  float* wsf = (float*)d_ws;
  ushort_t* qbA  = (ushort_t*)(wsf);            // [65536][32] bf16  [0 .. 1,048,576)
  ushort_t* kbA  = (ushort_t*)(wsf + 1048576);  //                   [1,048,576 .. 2,097,152)
  ushort_t* vtA  = (ushort_t*)(wsf + 2097152);  // [B,32,S]          [2,097,152 .. 3,145,728)
  float*    part2= wsf + 4456448;               // [64,16,10]        [4,456,448 .. 4,466,688)
  float*    w1t  = wsf + 4466688;               // [10,20480]        ends 4,671,488
  ushort_t* qbB  = (ushort_t*)(wsf + 4671488);  // ends 5,195,776
  ushort_t* kbB  = (ushort_t*)(wsf + 5712384);  // B-buffers overlap dead c2 region
  ushort_t* vtB  = (ushort_t*)(wsf + 6760960);  //   (c2 consumed before attn1 writes B)
  float*    c2   = wsf + 5242880;               // [B,4,2048,5]      [5,242,880 .. 7,864,320)

  conv12_kernel<<<512, 256, 0, stream>>>(inp, cw1, cb1, cw2, cb2, c2, dw1, w1t);

  conv3_proj_kernel<<<256, 256, 0, stream>>>(c2, cw3, cb3, a1K, a1Q, a1V, qbA, kbA, vtA);
  // attn1: reads A, fused proj(layer2) -> B
  attn_kernel<true><<<dim3(16, 64), 256, 0, stream>>>(
      qbA, kbA, vtA, a2K, a2Q, a2V, qbB, kbB, vtB, nullptr, nullptr);
  // attn2: reads B, fused proj(layer3) -> A
  attn_kernel<true><<<dim3(16, 64), 256, 0, stream>>>(
      qbB, kbB, vtB, a3K, a3Q, a3V, qbA, kbA, vtA, nullptr, nullptr);
  // attn3: reads A, fused dense1 partial -> part2
  attn_kernel<false><<<dim3(16, 64), 256, 0, stream>>>(
      qbA, kbA, vtA, nullptr, nullptr, nullptr, nullptr, nullptr, nullptr,
      w1t, part2);

  dense_final<<<64, 64, 0, stream>>>(part2, db1, dw2, db2, dw3, db3, outp);
}